// Round 15
// baseline (142.842 us; speedup 1.0000x reference)
//
#include <hip/hip_runtime.h>
#include <stdint.h>

#define BATCH   2048
#define KDIM    4096
#define NDIM    11008

#define BM 128
#define BN 256
#define BK 128
#define NT (KDIM / BK)               // 32 K-tiles
#define BPK_ROWB 1024                // packed B row bytes = KDIM/4

// LDS map: A dbuf 2x16KB at 0/16384; B 4-deep 4x8KB at 32768+8192*i; 64KB
#define A0_OFF 0
#define A1_OFF 16384
#define B_BASE 32768

typedef __attribute__((ext_vector_type(4))) int i32x4;

typedef const __attribute__((address_space(1))) char glob_char;
typedef __attribute__((address_space(3))) char lds_char;

__device__ __forceinline__ unsigned pack4(i32x4 v) {
  return  ((unsigned)v.x & 0xFFu)
        | (((unsigned)v.y & 0xFFu) << 8)
        | (((unsigned)v.z & 0xFFu) << 16)
        | (((unsigned)v.w)         << 24);
}

// A: int32 (values in [-128,127]) -> packed int8, 4 elements per thread
__global__ __launch_bounds__(256) void convert_i32_i8(const int* __restrict__ src,
                                                      unsigned* __restrict__ dst,
                                                      int n4) {
  int idx = blockIdx.x * 256 + threadIdx.x;
  if (idx >= n4) return;
  i32x4 v = ((const i32x4*)src)[idx];
  dst[idx] = pack4(v);
}

// B: ternary int32 -> 2-bit packed (R12-R14-validated). Element e of word at
// bits [8*(e&3) + 2*(e>>2)]; LDS bank swizzle baked in: word i%8 stored at
// slot (i%8)^(row&7) within its 32B group.
__global__ __launch_bounds__(256) void convert_w2(const int* __restrict__ src,
                                                  unsigned* __restrict__ dst) {
  const int f = blockIdx.x * 256 + threadIdx.x;
  const int r = f >> 8;
  const int i = f & 255;
  const int* p = src + (size_t)r * KDIM + i * 16;
  unsigned w = 0;
#pragma unroll
  for (int e = 0; e < 16; ++e) {
    const unsigned v = (unsigned)p[e] & 3u;
    w |= v << (8 * (e & 3) + 2 * (e >> 2));
  }
  const int slot = (i & 7) ^ (r & 7);
  dst[(size_t)r * 256 + (i >> 3) * 8 + slot] = w;
}

// decode 16x 2-bit ternary -> 16 int8 (k-order): (x&M1) | ((y<<7)-y), y=x&M2
__device__ __forceinline__ i32x4 dec2(unsigned w) {
  const unsigned M1 = 0x01010101u, M2 = 0x02020202u;
  i32x4 r;
  { unsigned x = w;      unsigned y = x & M2; r.x = (int)((x & M1) | ((y << 7) - y)); }
  { unsigned x = w >> 2; unsigned y = x & M2; r.y = (int)((x & M1) | ((y << 7) - y)); }
  { unsigned x = w >> 4; unsigned y = x & M2; r.z = (int)((x & M1) | ((y << 7) - y)); }
  { unsigned x = w >> 6; unsigned y = x & M2; r.w = (int)((x & M1) | ((y << 7) - y)); }
  return r;
}

// C[2048][11008] = A[2048][4096] * W[11008][4096]^T via mfma_i32_16x16x64_i8.
// R15 = R14 skeleton with wave-tile 128x64 (BN=256, 1m x 4n):
//  - A-LDS-read per op HALVES (1/(2*wave_n)): per CU 8 waves x 16KB A-reads
//    + 48KB staging writes per MFMA window -> LDS port unsaturated (R13/R14
//    had 258KB vs a ~250KB window).
//  - B-decode stays unique-minimal (each wave owns a 64-col B slice).
//  - staged bytes/op 2.86e-3 -> staging floor 54us; MFMA floor 70us at the
//    G=688 67% tail (accepted: internal-limit relief > tail loss).
//  - acc[8][4]=128 regs -> __launch_bounds__(256,2) (256-reg budget, no
//    spill per R9 lesson); 64KB LDS -> 2 blocks/CU (R7 precedent: 2 blk/CU
//    + 4-wave blocks hit 103% of its staging ceiling).
//  - A depth-1 dbuf (L2-resident panel), B depth-2 over 4 x 8KB buffers;
//    issue A(t+1)x4 then B(t+2)x2; ONE counted vmcnt(2) per KT retires
//    {B(t+1)x2, A(t+1)x4}, leaves B(t+2)x2 in flight. x4-unrolled loop ->
//    compile-time LDS offsets. No manual lgkmcnt/sched_barrier (R6 lesson).
//  - Raster: mt = wg/43 -> each XCD holds 2 A-slices (1MB, L2-resident),
//    B-panels stream once. XCD swizzle bijective (688 % 8 == 0).
__global__ __launch_bounds__(256, 2) void ternary_gemm(const char* __restrict__ A8,
                                                       const unsigned* __restrict__ B2,
                                                       const float* __restrict__ scale,
                                                       const float* __restrict__ bias,
                                                       float* __restrict__ out) {
  __shared__ char lds[65536];          // 64KB -> 2 blocks/CU

  const int tid  = threadIdx.x;
  const int wid  = tid >> 6;
  const int lane = tid & 63;

  // XCD swizzle + mt-outer raster: wg = xcd*86 + local; mt = wg/43, nt = wg%43
  const int wg = (blockIdx.x & 7) * 86 + (blockIdx.x >> 3);
  const int mt = wg / 43;              // 0..15
  const int nt = wg % 43;              // 0..42
  const int arow0 = mt * BM;
  const int brow0 = nt * BN;

  const int wc = wid;                  // 0..3 : 64-col slice (unique B per wave)
  const int rsub = lane & 15;
  const int sgrp = lane >> 4;

  // A staging: 4 rounds of 256 thr x 16B (32 rows of 128B each)
  const int srowA = tid >> 3;
  const int slotA = (tid & 7) ^ (srowA & 7);
  // B staging: 2 rounds of 256 thr x 16B (128 rows of 32B each), linear copy
  const int srowB = tid >> 1;
  const int shalfB = (tid & 1) * 16;

  const char* gAbase = A8 + (size_t)(arow0 + srowA) * KDIM + slotA * 16;
  const char* gBbase = (const char*)B2 + (size_t)(brow0 + srowB) * BPK_ROWB + shalfB;

  auto stageA = [&](int Adst, int kt) {
#pragma unroll
    for (int rr = 0; rr < 4; ++rr) {
      __builtin_amdgcn_global_load_lds(
          (glob_char*)(gAbase + (size_t)rr * 32 * KDIM + kt * BK),
          (lds_char*)(lds + Adst + rr * 4096 + wid * 1024), 16, 0, 0);
    }
  };
  auto stageB = [&](int Bdst, int kt) {
#pragma unroll
    for (int rr = 0; rr < 2; ++rr) {
      __builtin_amdgcn_global_load_lds(
          (glob_char*)(gBbase + (size_t)rr * 128 * BPK_ROWB + kt * (BK / 4)),
          (lds_char*)(lds + Bdst + rr * 4096 + wid * 1024), 16, 0, 0);
    }
  };

  // loop-invariant fragment byte-offsets (buffer-relative)
  int offA[8][2], offB[4][2];
#pragma unroll
  for (int m = 0; m < 8; ++m) {
    const int row = m * 16 + rsub;
#pragma unroll
    for (int ks = 0; ks < 2; ++ks) {
      const int p = (ks * 4 + sgrp) ^ (row & 7);
      offA[m][ks] = row * 128 + p * 16;
    }
  }
#pragma unroll
  for (int n = 0; n < 4; ++n) {
    const int row = wc * 64 + n * 16 + rsub;
#pragma unroll
    for (int ks = 0; ks < 2; ++ks) {
      const int p = (ks * 4 + sgrp) ^ (row & 7);
      offB[n][ks] = row * 32 + p * 4;
    }
  }

  i32x4 acc[8][4];
#pragma unroll
  for (int m = 0; m < 8; ++m)
#pragma unroll
    for (int n = 0; n < 4; ++n)
      acc[m][n] = (i32x4){0, 0, 0, 0};

  // prologue: A(0)->A0, B(0)->B0, B(1)->B1; full drain once
  stageA(A0_OFF, 0);
  stageB(B_BASE, 0);
  stageB(B_BASE + 8192, 1);
  asm volatile("s_waitcnt vmcnt(0)" ::: "memory");
  __builtin_amdgcn_s_barrier();

  // one K-step: stage A(t+1)->Anxt (4 loads), B(t+2)->Bpf (2 loads);
  // compute from Acur/Bcur; vmcnt(2) retires {B(t+1)x2, A(t+1)x4},
  // leaves B(t+2)x2 in flight; barrier.
  auto step = [&](int Acur, int Anxt, int Bcur, int Bpf, int t) {
    const int ktA = (t + 1 < NT) ? t + 1 : NT - 1;
    const int ktB = (t + 2 < NT) ? t + 2 : NT - 1;
    stageA(Anxt, ktA);
    stageB(Bpf, ktB);
#pragma unroll
    for (int ks = 0; ks < 2; ++ks) {
      i32x4 a0 = *(const i32x4*)(lds + Acur + offA[0][ks]);
      i32x4 a1 = *(const i32x4*)(lds + Acur + offA[1][ks]);
      i32x4 a2 = *(const i32x4*)(lds + Acur + offA[2][ks]);
      i32x4 a3 = *(const i32x4*)(lds + Acur + offA[3][ks]);
      i32x4 a4 = *(const i32x4*)(lds + Acur + offA[4][ks]);
      i32x4 a5 = *(const i32x4*)(lds + Acur + offA[5][ks]);
      i32x4 a6 = *(const i32x4*)(lds + Acur + offA[6][ks]);
      i32x4 a7 = *(const i32x4*)(lds + Acur + offA[7][ks]);
      unsigned w0 = *(const unsigned*)(lds + Bcur + offB[0][ks]);
      unsigned w1 = *(const unsigned*)(lds + Bcur + offB[1][ks]);
      unsigned w2 = *(const unsigned*)(lds + Bcur + offB[2][ks]);
      unsigned w3 = *(const unsigned*)(lds + Bcur + offB[3][ks]);
      i32x4 b0 = dec2(w0);
      i32x4 b1 = dec2(w1);
      i32x4 b2 = dec2(w2);
      i32x4 b3 = dec2(w3);
      __builtin_amdgcn_s_setprio(1);
      acc[0][0] = __builtin_amdgcn_mfma_i32_16x16x64_i8(a0, b0, acc[0][0], 0, 0, 0);
      acc[1][0] = __builtin_amdgcn_mfma_i32_16x16x64_i8(a1, b0, acc[1][0], 0, 0, 0);
      acc[2][0] = __builtin_amdgcn_mfma_i32_16x16x64_i8(a2, b0, acc[2][0], 0, 0, 0);
      acc[3][0] = __builtin_amdgcn_mfma_i32_16x16x64_i8(a3, b0, acc[3][0], 0, 0, 0);
      acc[4][0] = __builtin_amdgcn_mfma_i32_16x16x64_i8(a4, b0, acc[4][0], 0, 0, 0);
      acc[5][0] = __builtin_amdgcn_mfma_i32_16x16x64_i8(a5, b0, acc[5][0], 0, 0, 0);
      acc[6][0] = __builtin_amdgcn_mfma_i32_16x16x64_i8(a6, b0, acc[6][0], 0, 0, 0);
      acc[7][0] = __builtin_amdgcn_mfma_i32_16x16x64_i8(a7, b0, acc[7][0], 0, 0, 0);
      acc[0][1] = __builtin_amdgcn_mfma_i32_16x16x64_i8(a0, b1, acc[0][1], 0, 0, 0);
      acc[1][1] = __builtin_amdgcn_mfma_i32_16x16x64_i8(a1, b1, acc[1][1], 0, 0, 0);
      acc[2][1] = __builtin_amdgcn_mfma_i32_16x16x64_i8(a2, b1, acc[2][1], 0, 0, 0);
      acc[3][1] = __builtin_amdgcn_mfma_i32_16x16x64_i8(a3, b1, acc[3][1], 0, 0, 0);
      acc[4][1] = __builtin_amdgcn_mfma_i32_16x16x64_i8(a4, b1, acc[4][1], 0, 0, 0);
      acc[5][1] = __builtin_amdgcn_mfma_i32_16x16x64_i8(a5, b1, acc[5][1], 0, 0, 0);
      acc[6][1] = __builtin_amdgcn_mfma_i32_16x16x64_i8(a6, b1, acc[6][1], 0, 0, 0);
      acc[7][1] = __builtin_amdgcn_mfma_i32_16x16x64_i8(a7, b1, acc[7][1], 0, 0, 0);
      acc[0][2] = __builtin_amdgcn_mfma_i32_16x16x64_i8(a0, b2, acc[0][2], 0, 0, 0);
      acc[1][2] = __builtin_amdgcn_mfma_i32_16x16x64_i8(a1, b2, acc[1][2], 0, 0, 0);
      acc[2][2] = __builtin_amdgcn_mfma_i32_16x16x64_i8(a2, b2, acc[2][2], 0, 0, 0);
      acc[3][2] = __builtin_amdgcn_mfma_i32_16x16x64_i8(a3, b2, acc[3][2], 0, 0, 0);
      acc[4][2] = __builtin_amdgcn_mfma_i32_16x16x64_i8(a4, b2, acc[4][2], 0, 0, 0);
      acc[5][2] = __builtin_amdgcn_mfma_i32_16x16x64_i8(a5, b2, acc[5][2], 0, 0, 0);
      acc[6][2] = __builtin_amdgcn_mfma_i32_16x16x64_i8(a6, b2, acc[6][2], 0, 0, 0);
      acc[7][2] = __builtin_amdgcn_mfma_i32_16x16x64_i8(a7, b2, acc[7][2], 0, 0, 0);
      acc[0][3] = __builtin_amdgcn_mfma_i32_16x16x64_i8(a0, b3, acc[0][3], 0, 0, 0);
      acc[1][3] = __builtin_amdgcn_mfma_i32_16x16x64_i8(a1, b3, acc[1][3], 0, 0, 0);
      acc[2][3] = __builtin_amdgcn_mfma_i32_16x16x64_i8(a2, b3, acc[2][3], 0, 0, 0);
      acc[3][3] = __builtin_amdgcn_mfma_i32_16x16x64_i8(a3, b3, acc[3][3], 0, 0, 0);
      acc[4][3] = __builtin_amdgcn_mfma_i32_16x16x64_i8(a4, b3, acc[4][3], 0, 0, 0);
      acc[5][3] = __builtin_amdgcn_mfma_i32_16x16x64_i8(a5, b3, acc[5][3], 0, 0, 0);
      acc[6][3] = __builtin_amdgcn_mfma_i32_16x16x64_i8(a6, b3, acc[6][3], 0, 0, 0);
      acc[7][3] = __builtin_amdgcn_mfma_i32_16x16x64_i8(a7, b3, acc[7][3], 0, 0, 0);
      __builtin_amdgcn_s_setprio(0);
    }
    asm volatile("s_waitcnt vmcnt(2)" ::: "memory");
    __builtin_amdgcn_s_barrier();
  };

  for (int t4 = 0; t4 < NT; t4 += 4) {
    step(A0_OFF, A1_OFF, B_BASE,         B_BASE + 16384, t4);
    step(A1_OFF, A0_OFF, B_BASE +  8192, B_BASE + 24576, t4 + 1);
    step(A0_OFF, A1_OFF, B_BASE + 16384, B_BASE,         t4 + 2);
    step(A1_OFF, A0_OFF, B_BASE + 24576, B_BASE +  8192, t4 + 3);
  }

  // Epilogue (validated R1-R14): C/D col = lane&15, row = (lane>>4)*4 + reg
  const int crow = sgrp * 4;
#pragma unroll
  for (int n = 0; n < 4; ++n) {
    const int col = brow0 + wc * 64 + n * 16 + rsub;
    const float sc = scale[col];
    const float bs = bias[col];
#pragma unroll
    for (int m = 0; m < 8; ++m) {
      const int r0 = arow0 + m * 16 + crow;
#pragma unroll
      for (int j = 0; j < 4; ++j) {
        out[(size_t)(r0 + j) * NDIM + col] = (float)acc[m][n][j] * sc + bs;
      }
    }
  }
}

extern "C" void kernel_launch(void* const* d_in, const int* in_sizes, int n_in,
                              void* d_out, int out_size, void* d_ws, size_t ws_size,
                              hipStream_t stream) {
  const int*   input  = (const int*)d_in[0];     // [2048][4096] int32
  const int*   weight = (const int*)d_in[1];     // [11008][4096] int32 in {-1,0,1}
  const float* scale  = (const float*)d_in[2];   // [11008]
  const float* bias   = (const float*)d_in[3];   // [11008]
  float*       out    = (float*)d_out;           // [2048][11008] fp32

  const size_t needA = (size_t)BATCH * KDIM;          // 8 MB int8

  char*     A8  = (char*)d_ws;
  unsigned* Bpk = (unsigned*)(A8 + needA);            // 11 MB 2-bit packed
  const int nA4 = (int)(needA / 4);
  convert_i32_i8<<<(nA4 + 255) / 256, 256, 0, stream>>>(input, (unsigned*)A8, nA4);
  convert_w2<<<NDIM * (KDIM / 16) / 256, 256, 0, stream>>>(weight, Bpk);

  const dim3 grid((BATCH / BM) * (NDIM / BN));   // 16 * 43 = 688
  const dim3 block(256);
  ternary_gemm<<<grid, block, 0, stream>>>(A8, Bpk, scale, bias, out);
  (void)ws_size; (void)n_in; (void)in_sizes; (void)out_size;
}

// Round 16
// 142.809 us; speedup vs baseline: 1.0002x; 1.0002x over previous
//
#include <hip/hip_runtime.h>
#include <stdint.h>

#define BATCH   2048
#define KDIM    4096
#define NDIM    11008

#define BM 128
#define BN 256
#define BK 128
#define NT (KDIM / BK)               // 32 K-tiles
#define BPK_ROWB 1024                // packed B row bytes = KDIM/4

// LDS map: A dbuf 2x16KB at 0/16384; B 4-deep 4x8KB at 32768+8192*i; 64KB
#define A0_OFF 0
#define A1_OFF 16384
#define B_BASE 32768

typedef __attribute__((ext_vector_type(4))) int i32x4;

typedef const __attribute__((address_space(1))) char glob_char;
typedef __attribute__((address_space(3))) char lds_char;

__device__ __forceinline__ unsigned pack4(i32x4 v) {
  return  ((unsigned)v.x & 0xFFu)
        | (((unsigned)v.y & 0xFFu) << 8)
        | (((unsigned)v.z & 0xFFu) << 16)
        | (((unsigned)v.w)         << 24);
}

// A: int32 (values in [-128,127]) -> packed int8, 4 elements per thread
__global__ __launch_bounds__(256) void convert_i32_i8(const int* __restrict__ src,
                                                      unsigned* __restrict__ dst,
                                                      int n4) {
  int idx = blockIdx.x * 256 + threadIdx.x;
  if (idx >= n4) return;
  i32x4 v = ((const i32x4*)src)[idx];
  dst[idx] = pack4(v);
}

// B: ternary int32 -> 2-bit packed (R12-R14-validated). Element e of word at
// bits [8*(e&3) + 2*(e>>2)]; LDS bank swizzle baked in: word i%8 stored at
// slot (i%8)^(row&7) within its 32B group.
__global__ __launch_bounds__(256) void convert_w2(const int* __restrict__ src,
                                                  unsigned* __restrict__ dst) {
  const int f = blockIdx.x * 256 + threadIdx.x;
  const int r = f >> 8;
  const int i = f & 255;
  const int* p = src + (size_t)r * KDIM + i * 16;
  unsigned w = 0;
#pragma unroll
  for (int e = 0; e < 16; ++e) {
    const unsigned v = (unsigned)p[e] & 3u;
    w |= v << (8 * (e & 3) + 2 * (e >> 2));
  }
  const int slot = (i & 7) ^ (r & 7);
  dst[(size_t)r * 256 + (i >> 3) * 8 + slot] = w;
}

// decode 16x 2-bit ternary -> 16 int8 (k-order): (x&M1) | ((y<<7)-y), y=x&M2
__device__ __forceinline__ i32x4 dec2(unsigned w) {
  const unsigned M1 = 0x01010101u, M2 = 0x02020202u;
  i32x4 r;
  { unsigned x = w;      unsigned y = x & M2; r.x = (int)((x & M1) | ((y << 7) - y)); }
  { unsigned x = w >> 2; unsigned y = x & M2; r.y = (int)((x & M1) | ((y << 7) - y)); }
  { unsigned x = w >> 4; unsigned y = x & M2; r.z = (int)((x & M1) | ((y << 7) - y)); }
  { unsigned x = w >> 6; unsigned y = x & M2; r.w = (int)((x & M1) | ((y << 7) - y)); }
  return r;
}

// C[2048][11008] = A[2048][4096] * W[11008][4096]^T via mfma_i32_16x16x64_i8.
// R15 = R14 skeleton with wave-tile 128x64 (BN=256, 1m x 4n):
//  - A-LDS-read per op HALVES (1/(2*wave_n)): per CU 8 waves x 16KB A-reads
//    + 48KB staging writes per MFMA window -> LDS port unsaturated (R13/R14
//    had 258KB vs a ~250KB window).
//  - B-decode stays unique-minimal (each wave owns a 64-col B slice).
//  - staged bytes/op 2.86e-3 -> staging floor 54us; MFMA floor 70us at the
//    G=688 67% tail (accepted: internal-limit relief > tail loss).
//  - acc[8][4]=128 regs -> __launch_bounds__(256,2) (256-reg budget, no
//    spill per R9 lesson); 64KB LDS -> 2 blocks/CU (R7 precedent: 2 blk/CU
//    + 4-wave blocks hit 103% of its staging ceiling).
//  - A depth-1 dbuf (L2-resident panel), B depth-2 over 4 x 8KB buffers;
//    issue A(t+1)x4 then B(t+2)x2; ONE counted vmcnt(2) per KT retires
//    {B(t+1)x2, A(t+1)x4}, leaves B(t+2)x2 in flight. x4-unrolled loop ->
//    compile-time LDS offsets. No manual lgkmcnt/sched_barrier (R6 lesson).
//  - Raster: mt = wg/43 -> each XCD holds 2 A-slices (1MB, L2-resident),
//    B-panels stream once. XCD swizzle bijective (688 % 8 == 0).
__global__ __launch_bounds__(256, 2) void ternary_gemm(const char* __restrict__ A8,
                                                       const unsigned* __restrict__ B2,
                                                       const float* __restrict__ scale,
                                                       const float* __restrict__ bias,
                                                       float* __restrict__ out) {
  __shared__ char lds[65536];          // 64KB -> 2 blocks/CU

  const int tid  = threadIdx.x;
  const int wid  = tid >> 6;
  const int lane = tid & 63;

  // XCD swizzle + mt-outer raster: wg = xcd*86 + local; mt = wg/43, nt = wg%43
  const int wg = (blockIdx.x & 7) * 86 + (blockIdx.x >> 3);
  const int mt = wg / 43;              // 0..15
  const int nt = wg % 43;              // 0..42
  const int arow0 = mt * BM;
  const int brow0 = nt * BN;

  const int wc = wid;                  // 0..3 : 64-col slice (unique B per wave)
  const int rsub = lane & 15;
  const int sgrp = lane >> 4;

  // A staging: 4 rounds of 256 thr x 16B (32 rows of 128B each)
  const int srowA = tid >> 3;
  const int slotA = (tid & 7) ^ (srowA & 7);
  // B staging: 2 rounds of 256 thr x 16B (128 rows of 32B each), linear copy
  const int srowB = tid >> 1;
  const int shalfB = (tid & 1) * 16;

  const char* gAbase = A8 + (size_t)(arow0 + srowA) * KDIM + slotA * 16;
  const char* gBbase = (const char*)B2 + (size_t)(brow0 + srowB) * BPK_ROWB + shalfB;

  auto stageA = [&](int Adst, int kt) {
#pragma unroll
    for (int rr = 0; rr < 4; ++rr) {
      __builtin_amdgcn_global_load_lds(
          (glob_char*)(gAbase + (size_t)rr * 32 * KDIM + kt * BK),
          (lds_char*)(lds + Adst + rr * 4096 + wid * 1024), 16, 0, 0);
    }
  };
  auto stageB = [&](int Bdst, int kt) {
#pragma unroll
    for (int rr = 0; rr < 2; ++rr) {
      __builtin_amdgcn_global_load_lds(
          (glob_char*)(gBbase + (size_t)rr * 128 * BPK_ROWB + kt * (BK / 4)),
          (lds_char*)(lds + Bdst + rr * 4096 + wid * 1024), 16, 0, 0);
    }
  };

  // loop-invariant fragment byte-offsets (buffer-relative)
  int offA[8][2], offB[4][2];
#pragma unroll
  for (int m = 0; m < 8; ++m) {
    const int row = m * 16 + rsub;
#pragma unroll
    for (int ks = 0; ks < 2; ++ks) {
      const int p = (ks * 4 + sgrp) ^ (row & 7);
      offA[m][ks] = row * 128 + p * 16;
    }
  }
#pragma unroll
  for (int n = 0; n < 4; ++n) {
    const int row = wc * 64 + n * 16 + rsub;
#pragma unroll
    for (int ks = 0; ks < 2; ++ks) {
      const int p = (ks * 4 + sgrp) ^ (row & 7);
      offB[n][ks] = row * 32 + p * 4;
    }
  }

  i32x4 acc[8][4];
#pragma unroll
  for (int m = 0; m < 8; ++m)
#pragma unroll
    for (int n = 0; n < 4; ++n)
      acc[m][n] = (i32x4){0, 0, 0, 0};

  // prologue: A(0)->A0, B(0)->B0, B(1)->B1; full drain once
  stageA(A0_OFF, 0);
  stageB(B_BASE, 0);
  stageB(B_BASE + 8192, 1);
  asm volatile("s_waitcnt vmcnt(0)" ::: "memory");
  __builtin_amdgcn_s_barrier();

  // one K-step: stage A(t+1)->Anxt (4 loads), B(t+2)->Bpf (2 loads);
  // compute from Acur/Bcur; vmcnt(2) retires {B(t+1)x2, A(t+1)x4},
  // leaves B(t+2)x2 in flight; barrier.
  auto step = [&](int Acur, int Anxt, int Bcur, int Bpf, int t) {
    const int ktA = (t + 1 < NT) ? t + 1 : NT - 1;
    const int ktB = (t + 2 < NT) ? t + 2 : NT - 1;
    stageA(Anxt, ktA);
    stageB(Bpf, ktB);
#pragma unroll
    for (int ks = 0; ks < 2; ++ks) {
      i32x4 a0 = *(const i32x4*)(lds + Acur + offA[0][ks]);
      i32x4 a1 = *(const i32x4*)(lds + Acur + offA[1][ks]);
      i32x4 a2 = *(const i32x4*)(lds + Acur + offA[2][ks]);
      i32x4 a3 = *(const i32x4*)(lds + Acur + offA[3][ks]);
      i32x4 a4 = *(const i32x4*)(lds + Acur + offA[4][ks]);
      i32x4 a5 = *(const i32x4*)(lds + Acur + offA[5][ks]);
      i32x4 a6 = *(const i32x4*)(lds + Acur + offA[6][ks]);
      i32x4 a7 = *(const i32x4*)(lds + Acur + offA[7][ks]);
      unsigned w0 = *(const unsigned*)(lds + Bcur + offB[0][ks]);
      unsigned w1 = *(const unsigned*)(lds + Bcur + offB[1][ks]);
      unsigned w2 = *(const unsigned*)(lds + Bcur + offB[2][ks]);
      unsigned w3 = *(const unsigned*)(lds + Bcur + offB[3][ks]);
      i32x4 b0 = dec2(w0);
      i32x4 b1 = dec2(w1);
      i32x4 b2 = dec2(w2);
      i32x4 b3 = dec2(w3);
      __builtin_amdgcn_s_setprio(1);
      acc[0][0] = __builtin_amdgcn_mfma_i32_16x16x64_i8(a0, b0, acc[0][0], 0, 0, 0);
      acc[1][0] = __builtin_amdgcn_mfma_i32_16x16x64_i8(a1, b0, acc[1][0], 0, 0, 0);
      acc[2][0] = __builtin_amdgcn_mfma_i32_16x16x64_i8(a2, b0, acc[2][0], 0, 0, 0);
      acc[3][0] = __builtin_amdgcn_mfma_i32_16x16x64_i8(a3, b0, acc[3][0], 0, 0, 0);
      acc[4][0] = __builtin_amdgcn_mfma_i32_16x16x64_i8(a4, b0, acc[4][0], 0, 0, 0);
      acc[5][0] = __builtin_amdgcn_mfma_i32_16x16x64_i8(a5, b0, acc[5][0], 0, 0, 0);
      acc[6][0] = __builtin_amdgcn_mfma_i32_16x16x64_i8(a6, b0, acc[6][0], 0, 0, 0);
      acc[7][0] = __builtin_amdgcn_mfma_i32_16x16x64_i8(a7, b0, acc[7][0], 0, 0, 0);
      acc[0][1] = __builtin_amdgcn_mfma_i32_16x16x64_i8(a0, b1, acc[0][1], 0, 0, 0);
      acc[1][1] = __builtin_amdgcn_mfma_i32_16x16x64_i8(a1, b1, acc[1][1], 0, 0, 0);
      acc[2][1] = __builtin_amdgcn_mfma_i32_16x16x64_i8(a2, b1, acc[2][1], 0, 0, 0);
      acc[3][1] = __builtin_amdgcn_mfma_i32_16x16x64_i8(a3, b1, acc[3][1], 0, 0, 0);
      acc[4][1] = __builtin_amdgcn_mfma_i32_16x16x64_i8(a4, b1, acc[4][1], 0, 0, 0);
      acc[5][1] = __builtin_amdgcn_mfma_i32_16x16x64_i8(a5, b1, acc[5][1], 0, 0, 0);
      acc[6][1] = __builtin_amdgcn_mfma_i32_16x16x64_i8(a6, b1, acc[6][1], 0, 0, 0);
      acc[7][1] = __builtin_amdgcn_mfma_i32_16x16x64_i8(a7, b1, acc[7][1], 0, 0, 0);
      acc[0][2] = __builtin_amdgcn_mfma_i32_16x16x64_i8(a0, b2, acc[0][2], 0, 0, 0);
      acc[1][2] = __builtin_amdgcn_mfma_i32_16x16x64_i8(a1, b2, acc[1][2], 0, 0, 0);
      acc[2][2] = __builtin_amdgcn_mfma_i32_16x16x64_i8(a2, b2, acc[2][2], 0, 0, 0);
      acc[3][2] = __builtin_amdgcn_mfma_i32_16x16x64_i8(a3, b2, acc[3][2], 0, 0, 0);
      acc[4][2] = __builtin_amdgcn_mfma_i32_16x16x64_i8(a4, b2, acc[4][2], 0, 0, 0);
      acc[5][2] = __builtin_amdgcn_mfma_i32_16x16x64_i8(a5, b2, acc[5][2], 0, 0, 0);
      acc[6][2] = __builtin_amdgcn_mfma_i32_16x16x64_i8(a6, b2, acc[6][2], 0, 0, 0);
      acc[7][2] = __builtin_amdgcn_mfma_i32_16x16x64_i8(a7, b2, acc[7][2], 0, 0, 0);
      acc[0][3] = __builtin_amdgcn_mfma_i32_16x16x64_i8(a0, b3, acc[0][3], 0, 0, 0);
      acc[1][3] = __builtin_amdgcn_mfma_i32_16x16x64_i8(a1, b3, acc[1][3], 0, 0, 0);
      acc[2][3] = __builtin_amdgcn_mfma_i32_16x16x64_i8(a2, b3, acc[2][3], 0, 0, 0);
      acc[3][3] = __builtin_amdgcn_mfma_i32_16x16x64_i8(a3, b3, acc[3][3], 0, 0, 0);
      acc[4][3] = __builtin_amdgcn_mfma_i32_16x16x64_i8(a4, b3, acc[4][3], 0, 0, 0);
      acc[5][3] = __builtin_amdgcn_mfma_i32_16x16x64_i8(a5, b3, acc[5][3], 0, 0, 0);
      acc[6][3] = __builtin_amdgcn_mfma_i32_16x16x64_i8(a6, b3, acc[6][3], 0, 0, 0);
      acc[7][3] = __builtin_amdgcn_mfma_i32_16x16x64_i8(a7, b3, acc[7][3], 0, 0, 0);
      __builtin_amdgcn_s_setprio(0);
    }
    asm volatile("s_waitcnt vmcnt(2)" ::: "memory");
    __builtin_amdgcn_s_barrier();
  };

  for (int t4 = 0; t4 < NT; t4 += 4) {
    step(A0_OFF, A1_OFF, B_BASE,         B_BASE + 16384, t4);
    step(A1_OFF, A0_OFF, B_BASE +  8192, B_BASE + 24576, t4 + 1);
    step(A0_OFF, A1_OFF, B_BASE + 16384, B_BASE,         t4 + 2);
    step(A1_OFF, A0_OFF, B_BASE + 24576, B_BASE +  8192, t4 + 3);
  }

  // Epilogue (validated R1-R14): C/D col = lane&15, row = (lane>>4)*4 + reg
  const int crow = sgrp * 4;
#pragma unroll
  for (int n = 0; n < 4; ++n) {
    const int col = brow0 + wc * 64 + n * 16 + rsub;
    const float sc = scale[col];
    const float bs = bias[col];
#pragma unroll
    for (int m = 0; m < 8; ++m) {
      const int r0 = arow0 + m * 16 + crow;
#pragma unroll
      for (int j = 0; j < 4; ++j) {
        out[(size_t)(r0 + j) * NDIM + col] = (float)acc[m][n][j] * sc + bs;
      }
    }
  }
}

extern "C" void kernel_launch(void* const* d_in, const int* in_sizes, int n_in,
                              void* d_out, int out_size, void* d_ws, size_t ws_size,
                              hipStream_t stream) {
  const int*   input  = (const int*)d_in[0];     // [2048][4096] int32
  const int*   weight = (const int*)d_in[1];     // [11008][4096] int32 in {-1,0,1}
  const float* scale  = (const float*)d_in[2];   // [11008]
  const float* bias   = (const float*)d_in[3];   // [11008]
  float*       out    = (float*)d_out;           // [2048][11008] fp32

  const size_t needA = (size_t)BATCH * KDIM;          // 8 MB int8

  char*     A8  = (char*)d_ws;
  unsigned* Bpk = (unsigned*)(A8 + needA);            // 11 MB 2-bit packed
  const int nA4 = (int)(needA / 4);
  convert_i32_i8<<<(nA4 + 255) / 256, 256, 0, stream>>>(input, (unsigned*)A8, nA4);
  convert_w2<<<NDIM * (KDIM / 16) / 256, 256, 0, stream>>>(weight, Bpk);

  const dim3 grid((BATCH / BM) * (NDIM / BN));   // 16 * 43 = 688
  const dim3 block(256);
  ternary_gemm<<<grid, block, 0, stream>>>(A8, Bpk, scale, bias, out);
  (void)ws_size; (void)n_in; (void)in_sizes; (void)out_size;
}

// Round 17
// 142.251 us; speedup vs baseline: 1.0042x; 1.0039x over previous
//
#include <hip/hip_runtime.h>
#include <stdint.h>

#define BATCH   2048
#define KDIM    4096
#define NDIM    11008

#define BM 128
#define BN 128
#define BK 128
#define NT (KDIM / BK)               // 32 K-tiles
#define BPK_ROWB 1024                // packed B row bytes = KDIM/4

// LDS map: A dbuf 2x16KB at 0/16384; B 4-deep 4x4KB at 32768+4096*i; 48KB
// (48KB chosen so at most 3 blocks/CU fit: capacity 768 -> 89.6% tail)
#define A0_OFF 0
#define A1_OFF 16384
#define B_BASE 32768

typedef __attribute__((ext_vector_type(4))) int i32x4;

typedef const __attribute__((address_space(1))) char glob_char;
typedef __attribute__((address_space(3))) char lds_char;

__device__ __forceinline__ unsigned pack4(i32x4 v) {
  return  ((unsigned)v.x & 0xFFu)
        | (((unsigned)v.y & 0xFFu) << 8)
        | (((unsigned)v.z & 0xFFu) << 16)
        | (((unsigned)v.w)         << 24);
}

// A: int32 (values in [-128,127]) -> packed int8, 4 elements per thread
__global__ __launch_bounds__(256) void convert_i32_i8(const int* __restrict__ src,
                                                      unsigned* __restrict__ dst,
                                                      int n4) {
  int idx = blockIdx.x * 256 + threadIdx.x;
  if (idx >= n4) return;
  i32x4 v = ((const i32x4*)src)[idx];
  dst[idx] = pack4(v);
}

// B: ternary int32 -> 2-bit packed (R12-R16-validated). Element e of word at
// bits [8*(e&3) + 2*(e>>2)]; LDS bank swizzle baked in: word i%8 stored at
// slot (i%8)^(row&7) within its 32B group.
__global__ __launch_bounds__(256) void convert_w2(const int* __restrict__ src,
                                                  unsigned* __restrict__ dst) {
  const int f = blockIdx.x * 256 + threadIdx.x;
  const int r = f >> 8;
  const int i = f & 255;
  const int* p = src + (size_t)r * KDIM + i * 16;
  unsigned w = 0;
#pragma unroll
  for (int e = 0; e < 16; ++e) {
    const unsigned v = (unsigned)p[e] & 3u;
    w |= v << (8 * (e & 3) + 2 * (e >> 2));
  }
  const int slot = (i & 7) ^ (r & 7);
  dst[(size_t)r * 256 + (i >> 3) * 8 + slot] = w;
}

// decode 16x 2-bit ternary -> 16 int8 (k-order): (x&M1) | ((y<<7)-y), y=x&M2
__device__ __forceinline__ i32x4 dec2(unsigned w) {
  const unsigned M1 = 0x01010101u, M2 = 0x02020202u;
  i32x4 r;
  { unsigned x = w;      unsigned y = x & M2; r.x = (int)((x & M1) | ((y << 7) - y)); }
  { unsigned x = w >> 2; unsigned y = x & M2; r.y = (int)((x & M1) | ((y << 7) - y)); }
  { unsigned x = w >> 4; unsigned y = x & M2; r.z = (int)((x & M1) | ((y << 7) - y)); }
  { unsigned x = w >> 6; unsigned y = x & M2; r.w = (int)((x & M1) | ((y << 7) - y)); }
  return r;
}

// C[2048][11008] = A[2048][4096] * W[11008][4096]^T via mfma_i32_16x16x64_i8.
// R17 = wave_n=64 (R15's steady-state: halved A-LDS-reads, LDS-read pipe
// 54% not 81%) AT G=1376 (R14's 89.6% dispatch tail) via 2-WAVE BLOCKS:
//  - 128-thr blocks, BM=BN=128, 2 waves of 128x64 (1m x 2n); B-decode
//    unique per wave; A-bytes/op = 1/(2*64) = R15's.
//  - 48KB LDS -> exactly 3 blocks/CU (capacity 768; 40KB would let 4 fit
//    -> capacity 1024 -> 67% tail, deliberately avoided).
//  - Barriers sync only 2 waves (cheap); 3 independent blocks/CU slip to
//    cover each other's vmcnt/barrier stalls.
//  - A depth-1 dbuf (L2-resident panel raster), B depth-2 over 4 x 4KB;
//    per KT: issue A(t+1)x8 then B(t+2)x2; ONE counted vmcnt(2) retires
//    {B(t+1)x2, A(t+1)x8}, leaves B(t+2)x2 in flight. x4-unrolled loop ->
//    compile-time LDS offsets. No manual lgkmcnt/sched_barrier (R6 lesson).
//  - acc[8][4]=128 AGPR + ~110 VGPR = 238 < 256 at __launch_bounds__(128,2)
//    (R9 spill lesson respected).
// Swizzles/raster/epilogue identical to R14-R16 (validated).
__global__ __launch_bounds__(128, 2) void ternary_gemm(const char* __restrict__ A8,
                                                       const unsigned* __restrict__ B2,
                                                       const float* __restrict__ scale,
                                                       const float* __restrict__ bias,
                                                       float* __restrict__ out) {
  __shared__ char lds[49152];          // 48KB -> 3 blocks/CU

  const int tid  = threadIdx.x;        // 0..127
  const int wid  = tid >> 6;           // 0..1
  const int lane = tid & 63;

  // XCD swizzle (1376 % 8 == 0 -> bijective) + 4-wide mt-supertile raster
  const int wg  = (blockIdx.x & 7) * 172 + (blockIdx.x >> 3);
  const int mtq = wg / 344;
  const int r   = wg - mtq * 344;
  const int nt  = r >> 2;
  const int mt  = mtq * 4 + (r & 3);
  const int arow0 = mt * BM;
  const int brow0 = nt * BN;

  const int wc = wid;                  // 0..1 : 64-col slice (unique B per wave)
  const int rsub = lane & 15;
  const int sgrp = lane >> 4;

  // A staging: 8 rounds of 128 thr x 16B (16 rows of 128B each)
  const int srowA = tid >> 3;          // 0..15
  const int slotA = (tid & 7) ^ (srowA & 7);   // +rr*16 preserves row&7
  // B staging: 2 rounds of 128 thr x 16B (64 rows of 32B each), linear copy
  const int srowB = tid >> 1;          // 0..63
  const int shalfB = (tid & 1) * 16;

  const char* gAbase = A8 + (size_t)(arow0 + srowA) * KDIM + slotA * 16;
  const char* gBbase = (const char*)B2 + (size_t)(brow0 + srowB) * BPK_ROWB + shalfB;

  auto stageA = [&](int Adst, int kt) {
#pragma unroll
    for (int rr = 0; rr < 8; ++rr) {
      __builtin_amdgcn_global_load_lds(
          (glob_char*)(gAbase + (size_t)rr * 16 * KDIM + kt * BK),
          (lds_char*)(lds + Adst + rr * 2048 + wid * 1024), 16, 0, 0);
    }
  };
  auto stageB = [&](int Bdst, int kt) {
#pragma unroll
    for (int rr = 0; rr < 2; ++rr) {
      __builtin_amdgcn_global_load_lds(
          (glob_char*)(gBbase + (size_t)rr * 64 * BPK_ROWB + kt * (BK / 4)),
          (lds_char*)(lds + Bdst + rr * 2048 + wid * 1024), 16, 0, 0);
    }
  };

  // loop-invariant fragment byte-offsets (buffer-relative)
  int offA[8][2], offB[4][2];
#pragma unroll
  for (int m = 0; m < 8; ++m) {
    const int row = m * 16 + rsub;
#pragma unroll
    for (int ks = 0; ks < 2; ++ks) {
      const int p = (ks * 4 + sgrp) ^ (row & 7);
      offA[m][ks] = row * 128 + p * 16;
    }
  }
#pragma unroll
  for (int n = 0; n < 4; ++n) {
    const int row = wc * 64 + n * 16 + rsub;
#pragma unroll
    for (int ks = 0; ks < 2; ++ks) {
      const int p = (ks * 4 + sgrp) ^ (row & 7);
      offB[n][ks] = row * 32 + p * 4;
    }
  }

  i32x4 acc[8][4];
#pragma unroll
  for (int m = 0; m < 8; ++m)
#pragma unroll
    for (int n = 0; n < 4; ++n)
      acc[m][n] = (i32x4){0, 0, 0, 0};

  // prologue: A(0)->A0, B(0)->B0, B(1)->B1; full drain once
  stageA(A0_OFF, 0);
  stageB(B_BASE, 0);
  stageB(B_BASE + 4096, 1);
  asm volatile("s_waitcnt vmcnt(0)" ::: "memory");
  __builtin_amdgcn_s_barrier();

  // one K-step: stage A(t+1)->Anxt (8), B(t+2)->Bpf (2); compute Acur/Bcur;
  // vmcnt(2) retires {B(t+1)x2, A(t+1)x8}, leaves B(t+2)x2 in flight; barrier.
  auto step = [&](int Acur, int Anxt, int Bcur, int Bpf, int t) {
    const int ktA = (t + 1 < NT) ? t + 1 : NT - 1;
    const int ktB = (t + 2 < NT) ? t + 2 : NT - 1;
    stageA(Anxt, ktA);
    stageB(Bpf, ktB);
#pragma unroll
    for (int ks = 0; ks < 2; ++ks) {
      i32x4 a0 = *(const i32x4*)(lds + Acur + offA[0][ks]);
      i32x4 a1 = *(const i32x4*)(lds + Acur + offA[1][ks]);
      i32x4 a2 = *(const i32x4*)(lds + Acur + offA[2][ks]);
      i32x4 a3 = *(const i32x4*)(lds + Acur + offA[3][ks]);
      i32x4 a4 = *(const i32x4*)(lds + Acur + offA[4][ks]);
      i32x4 a5 = *(const i32x4*)(lds + Acur + offA[5][ks]);
      i32x4 a6 = *(const i32x4*)(lds + Acur + offA[6][ks]);
      i32x4 a7 = *(const i32x4*)(lds + Acur + offA[7][ks]);
      unsigned w0 = *(const unsigned*)(lds + Bcur + offB[0][ks]);
      unsigned w1 = *(const unsigned*)(lds + Bcur + offB[1][ks]);
      unsigned w2 = *(const unsigned*)(lds + Bcur + offB[2][ks]);
      unsigned w3 = *(const unsigned*)(lds + Bcur + offB[3][ks]);
      i32x4 b0 = dec2(w0);
      i32x4 b1 = dec2(w1);
      i32x4 b2 = dec2(w2);
      i32x4 b3 = dec2(w3);
      __builtin_amdgcn_s_setprio(1);
      acc[0][0] = __builtin_amdgcn_mfma_i32_16x16x64_i8(a0, b0, acc[0][0], 0, 0, 0);
      acc[1][0] = __builtin_amdgcn_mfma_i32_16x16x64_i8(a1, b0, acc[1][0], 0, 0, 0);
      acc[2][0] = __builtin_amdgcn_mfma_i32_16x16x64_i8(a2, b0, acc[2][0], 0, 0, 0);
      acc[3][0] = __builtin_amdgcn_mfma_i32_16x16x64_i8(a3, b0, acc[3][0], 0, 0, 0);
      acc[4][0] = __builtin_amdgcn_mfma_i32_16x16x64_i8(a4, b0, acc[4][0], 0, 0, 0);
      acc[5][0] = __builtin_amdgcn_mfma_i32_16x16x64_i8(a5, b0, acc[5][0], 0, 0, 0);
      acc[6][0] = __builtin_amdgcn_mfma_i32_16x16x64_i8(a6, b0, acc[6][0], 0, 0, 0);
      acc[7][0] = __builtin_amdgcn_mfma_i32_16x16x64_i8(a7, b0, acc[7][0], 0, 0, 0);
      acc[0][1] = __builtin_amdgcn_mfma_i32_16x16x64_i8(a0, b1, acc[0][1], 0, 0, 0);
      acc[1][1] = __builtin_amdgcn_mfma_i32_16x16x64_i8(a1, b1, acc[1][1], 0, 0, 0);
      acc[2][1] = __builtin_amdgcn_mfma_i32_16x16x64_i8(a2, b1, acc[2][1], 0, 0, 0);
      acc[3][1] = __builtin_amdgcn_mfma_i32_16x16x64_i8(a3, b1, acc[3][1], 0, 0, 0);
      acc[4][1] = __builtin_amdgcn_mfma_i32_16x16x64_i8(a4, b1, acc[4][1], 0, 0, 0);
      acc[5][1] = __builtin_amdgcn_mfma_i32_16x16x64_i8(a5, b1, acc[5][1], 0, 0, 0);
      acc[6][1] = __builtin_amdgcn_mfma_i32_16x16x64_i8(a6, b1, acc[6][1], 0, 0, 0);
      acc[7][1] = __builtin_amdgcn_mfma_i32_16x16x64_i8(a7, b1, acc[7][1], 0, 0, 0);
      acc[0][2] = __builtin_amdgcn_mfma_i32_16x16x64_i8(a0, b2, acc[0][2], 0, 0, 0);
      acc[1][2] = __builtin_amdgcn_mfma_i32_16x16x64_i8(a1, b2, acc[1][2], 0, 0, 0);
      acc[2][2] = __builtin_amdgcn_mfma_i32_16x16x64_i8(a2, b2, acc[2][2], 0, 0, 0);
      acc[3][2] = __builtin_amdgcn_mfma_i32_16x16x64_i8(a3, b2, acc[3][2], 0, 0, 0);
      acc[4][2] = __builtin_amdgcn_mfma_i32_16x16x64_i8(a4, b2, acc[4][2], 0, 0, 0);
      acc[5][2] = __builtin_amdgcn_mfma_i32_16x16x64_i8(a5, b2, acc[5][2], 0, 0, 0);
      acc[6][2] = __builtin_amdgcn_mfma_i32_16x16x64_i8(a6, b2, acc[6][2], 0, 0, 0);
      acc[7][2] = __builtin_amdgcn_mfma_i32_16x16x64_i8(a7, b2, acc[7][2], 0, 0, 0);
      acc[0][3] = __builtin_amdgcn_mfma_i32_16x16x64_i8(a0, b3, acc[0][3], 0, 0, 0);
      acc[1][3] = __builtin_amdgcn_mfma_i32_16x16x64_i8(a1, b3, acc[1][3], 0, 0, 0);
      acc[2][3] = __builtin_amdgcn_mfma_i32_16x16x64_i8(a2, b3, acc[2][3], 0, 0, 0);
      acc[3][3] = __builtin_amdgcn_mfma_i32_16x16x64_i8(a3, b3, acc[3][3], 0, 0, 0);
      acc[4][3] = __builtin_amdgcn_mfma_i32_16x16x64_i8(a4, b3, acc[4][3], 0, 0, 0);
      acc[5][3] = __builtin_amdgcn_mfma_i32_16x16x64_i8(a5, b3, acc[5][3], 0, 0, 0);
      acc[6][3] = __builtin_amdgcn_mfma_i32_16x16x64_i8(a6, b3, acc[6][3], 0, 0, 0);
      acc[7][3] = __builtin_amdgcn_mfma_i32_16x16x64_i8(a7, b3, acc[7][3], 0, 0, 0);
      __builtin_amdgcn_s_setprio(0);
    }
    asm volatile("s_waitcnt vmcnt(2)" ::: "memory");
    __builtin_amdgcn_s_barrier();
  };

  for (int t4 = 0; t4 < NT; t4 += 4) {
    step(A0_OFF, A1_OFF, B_BASE,         B_BASE +  8192, t4);
    step(A1_OFF, A0_OFF, B_BASE +  4096, B_BASE + 12288, t4 + 1);
    step(A0_OFF, A1_OFF, B_BASE +  8192, B_BASE,         t4 + 2);
    step(A1_OFF, A0_OFF, B_BASE + 12288, B_BASE +  4096, t4 + 3);
  }

  // Epilogue (validated R1-R16): C/D col = lane&15, row = (lane>>4)*4 + reg
  const int crow = sgrp * 4;
#pragma unroll
  for (int n = 0; n < 4; ++n) {
    const int col = brow0 + wc * 64 + n * 16 + rsub;
    const float sc = scale[col];
    const float bs = bias[col];
#pragma unroll
    for (int m = 0; m < 8; ++m) {
      const int r0 = arow0 + m * 16 + crow;
#pragma unroll
      for (int j = 0; j < 4; ++j) {
        out[(size_t)(r0 + j) * NDIM + col] = (float)acc[m][n][j] * sc + bs;
      }
    }
  }
}

extern "C" void kernel_launch(void* const* d_in, const int* in_sizes, int n_in,
                              void* d_out, int out_size, void* d_ws, size_t ws_size,
                              hipStream_t stream) {
  const int*   input  = (const int*)d_in[0];     // [2048][4096] int32
  const int*   weight = (const int*)d_in[1];     // [11008][4096] int32 in {-1,0,1}
  const float* scale  = (const float*)d_in[2];   // [11008]
  const float* bias   = (const float*)d_in[3];   // [11008]
  float*       out    = (float*)d_out;           // [2048][11008] fp32

  const size_t needA = (size_t)BATCH * KDIM;          // 8 MB int8

  char*     A8  = (char*)d_ws;
  unsigned* Bpk = (unsigned*)(A8 + needA);            // 11 MB 2-bit packed
  const int nA4 = (int)(needA / 4);
  convert_i32_i8<<<(nA4 + 255) / 256, 256, 0, stream>>>(input, (unsigned*)A8, nA4);
  convert_w2<<<NDIM * (KDIM / 16) / 256, 256, 0, stream>>>(weight, Bpk);

  const dim3 grid((BATCH / BM) * (NDIM / BN));   // 16 * 86 = 1376
  const dim3 block(128);
  ternary_gemm<<<grid, block, 0, stream>>>(A8, Bpk, scale, bias, out);
  (void)ws_size; (void)n_in; (void)in_sizes; (void)out_size;
}